// Round 1
// baseline (3096.109 us; speedup 1.0000x reference)
//
#include <hip/hip_runtime.h>
#include <cstdint>
#include <cstddef>

#define N_NODES 100000
#define N_EDGES 600000
#define F_IN    128
#define HID     256
#define NC      64

// ---------------- edge-index dtype detection -------------------------------
// Reference declares int64, but JAX without x64 silently yields int32.
// If the buffer is int64 (values < 2^31), every odd 32-bit word is 0.
__global__ void k_detect(const int* __restrict__ ei_words, int* __restrict__ mode) {
    if (blockIdx.x == 0 && threadIdx.x == 0) {
        int allz = 1;
        for (int i = 0; i < 64; ++i) {
            long long s = (long long)i * (N_EDGES - 1) / 63;
            if (ei_words[2 * s + 1] != 0) { allz = 0; break; }
        }
        *mode = allz;   // 1 => int64, 0 => int32
    }
}

__device__ __forceinline__ int load_idx(const void* ei, int m, long long i) {
    return m ? (int)((const long long*)ei)[i] : ((const int*)ei)[i];
}

// ---------------- degree / norm --------------------------------------------
__global__ void k_deg_init(float* __restrict__ dinv) {
    int n = blockIdx.x * blockDim.x + threadIdx.x;
    if (n < N_NODES) dinv[n] = 1.0f;   // self-loop
}

__global__ void k_deg_count(const void* __restrict__ ei, const int* __restrict__ mode,
                            float* __restrict__ dinv) {
    int e = blockIdx.x * blockDim.x + threadIdx.x;
    if (e >= N_EDGES) return;
    int d = load_idx(ei, *mode, (long long)N_EDGES + e);
    unsafeAtomicAdd(&dinv[d], 1.0f);   // exact integer adds: deterministic
}

__global__ void k_deg_rsqrt(float* __restrict__ dinv) {
    int n = blockIdx.x * blockDim.x + threadIdx.x;
    if (n < N_NODES) dinv[n] = rsqrtf(dinv[n]);
}

// ---------------- GEMM1: hx = x @ W1  (100000x128 @ 128x256) ---------------
// block = 256 threads (one per output col), 16 rows per block.
// x loads are block-uniform -> scalar loads; W1 loads coalesced.
__global__ void k_gemm1(const float* __restrict__ x, const float* __restrict__ W1,
                        float* __restrict__ hx) {
    const int col  = threadIdx.x;
    const int row0 = blockIdx.x * 16;
    float acc[16];
#pragma unroll
    for (int r = 0; r < 16; ++r) acc[r] = 0.0f;
    for (int k = 0; k < F_IN; ++k) {
        const float w = W1[k * HID + col];
#pragma unroll
        for (int r = 0; r < 16; ++r)
            acc[r] = fmaf(x[(size_t)(row0 + r) * F_IN + k], w, acc[r]);
    }
#pragma unroll
    for (int r = 0; r < 16; ++r)
        hx[(size_t)(row0 + r) * HID + col] = acc[r];
}

// ---------------- layer-1 aggregation --------------------------------------
// agg[n][f] = hx[n][f]*dinv[n]^2 + b1[f]   (self-loop + bias), then scatter.
__global__ void k_agg1_init(const float* __restrict__ hx, const float* __restrict__ dinv,
                            const float* __restrict__ b1, float* __restrict__ agg) {
    int i4 = blockIdx.x * blockDim.x + threadIdx.x;       // N*HID/4 items
    if (i4 >= N_NODES * HID / 4) return;
    int n  = i4 >> 6;            // / (HID/4)
    int f4 = i4 & 63;
    float sw = dinv[n]; sw *= sw;
    float4 v = ((const float4*)hx)[i4];
    const float4 b = ((const float4*)b1)[f4];
    float4 o;
    o.x = fmaf(v.x, sw, b.x); o.y = fmaf(v.y, sw, b.y);
    o.z = fmaf(v.z, sw, b.z); o.w = fmaf(v.w, sw, b.w);
    ((float4*)agg)[i4] = o;
}

__global__ void k_scatter1(const void* __restrict__ ei, const int* __restrict__ mode,
                           const float* __restrict__ dinv, const float* __restrict__ hx,
                           float* __restrict__ agg) {
    unsigned t = blockIdx.x * blockDim.x + threadIdx.x;   // E*64 threads
    int e = t >> 6, j = t & 63;
    if (e >= N_EDGES) return;
    int m = *mode;
    int s = load_idx(ei, m, e);
    int d = load_idx(ei, m, (long long)N_EDGES + e);
    float nr = dinv[s] * dinv[d];
    const float4 v = *(const float4*)(hx + (size_t)s * HID + j * 4);
    float* o = agg + (size_t)d * HID + j * 4;
    unsafeAtomicAdd(o + 0, v.x * nr);
    unsafeAtomicAdd(o + 1, v.y * nr);
    unsafeAtomicAdd(o + 2, v.z * nr);
    unsafeAtomicAdd(o + 3, v.w * nr);
}

__global__ void k_relu(float* __restrict__ agg) {
    int i4 = blockIdx.x * blockDim.x + threadIdx.x;       // N*HID/4
    if (i4 >= N_NODES * HID / 4) return;
    float4 v = ((float4*)agg)[i4];
    v.x = fmaxf(v.x, 0.f); v.y = fmaxf(v.y, 0.f);
    v.z = fmaxf(v.z, 0.f); v.w = fmaxf(v.w, 0.f);
    ((float4*)agg)[i4] = v;
}

// ---------------- GEMM2: hx2 = h @ W2  (100000x256 @ 256x64) ---------------
// block = 256: c = tid&63, group g = tid>>6 handles 4 rows; wave-uniform h loads.
__global__ void k_gemm2(const float* __restrict__ h, const float* __restrict__ W2,
                        float* __restrict__ hx2) {
    const int c = threadIdx.x & 63;
    const int g = threadIdx.x >> 6;
    const int row0 = blockIdx.x * 16 + g * 4;
    float acc[4] = {0.f, 0.f, 0.f, 0.f};
    for (int k = 0; k < HID; ++k) {
        const float w = W2[k * NC + c];
#pragma unroll
        for (int r = 0; r < 4; ++r)
            acc[r] = fmaf(h[(size_t)(row0 + r) * HID + k], w, acc[r]);
    }
#pragma unroll
    for (int r = 0; r < 4; ++r)
        hx2[(size_t)(row0 + r) * NC + c] = acc[r];
}

// ---------------- layer-2 aggregation (into d_out) -------------------------
__global__ void k_out_init(const float* __restrict__ hx2, const float* __restrict__ dinv,
                           const float* __restrict__ b2, float* __restrict__ out) {
    int i4 = blockIdx.x * blockDim.x + threadIdx.x;       // N*NC/4
    if (i4 >= N_NODES * NC / 4) return;
    int n  = i4 >> 4;            // / (NC/4)
    int c4 = i4 & 15;
    float sw = dinv[n]; sw *= sw;
    float4 v = ((const float4*)hx2)[i4];
    const float4 b = ((const float4*)b2)[c4];
    float4 o;
    o.x = fmaf(v.x, sw, b.x); o.y = fmaf(v.y, sw, b.y);
    o.z = fmaf(v.z, sw, b.z); o.w = fmaf(v.w, sw, b.w);
    ((float4*)out)[i4] = o;
}

__global__ void k_scatter2(const void* __restrict__ ei, const int* __restrict__ mode,
                           const float* __restrict__ dinv, const float* __restrict__ hx2,
                           float* __restrict__ out) {
    unsigned t = blockIdx.x * blockDim.x + threadIdx.x;   // E*16 threads
    int e = t >> 4, j = t & 15;
    if (e >= N_EDGES) return;
    int m = *mode;
    int s = load_idx(ei, m, e);
    int d = load_idx(ei, m, (long long)N_EDGES + e);
    float nr = dinv[s] * dinv[d];
    const float4 v = *(const float4*)(hx2 + (size_t)s * NC + j * 4);
    float* o = out + (size_t)d * NC + j * 4;
    unsafeAtomicAdd(o + 0, v.x * nr);
    unsafeAtomicAdd(o + 1, v.y * nr);
    unsafeAtomicAdd(o + 2, v.z * nr);
    unsafeAtomicAdd(o + 3, v.w * nr);
}

// ---------------- log_softmax over rows of [N,64] --------------------------
__global__ void k_logsoftmax(float* __restrict__ out) {
    int row  = blockIdx.x * 4 + (threadIdx.x >> 6);
    int lane = threadIdx.x & 63;
    if (row >= N_NODES) return;
    float v = out[(size_t)row * NC + lane];
    float mx = v;
#pragma unroll
    for (int o = 32; o; o >>= 1) mx = fmaxf(mx, __shfl_xor(mx, o));
    float ex = expf(v - mx);
    float s = ex;
#pragma unroll
    for (int o = 32; o; o >>= 1) s += __shfl_xor(s, o);
    out[(size_t)row * NC + lane] = v - mx - logf(s);
}

// ---------------- launch ----------------------------------------------------
extern "C" void kernel_launch(void* const* d_in, const int* in_sizes, int n_in,
                              void* d_out, int out_size, void* d_ws, size_t ws_size,
                              hipStream_t stream) {
    const float* x  = (const float*)d_in[0];
    const float* W1 = (const float*)d_in[1];
    const float* b1 = (const float*)d_in[2];
    const float* W2 = (const float*)d_in[3];
    const float* b2 = (const float*)d_in[4];
    const void*  ei = d_in[5];
    float* out = (float*)d_out;

    char* ws = (char*)d_ws;
    // layout: dinv [400000 B] | mode flag | hx [102.4 MB] | agg [102.4 MB]
    float* dinv = (float*)ws;
    int*   mode = (int*)(ws + 400000);
    float* hx   = (float*)(ws + 401408);                 // N*HID floats (hx2 reuses)
    float* agg  = (float*)(ws + 401408 + (size_t)N_NODES * HID * 4);

    k_detect<<<1, 64, 0, stream>>>((const int*)ei, mode);

    k_deg_init<<<(N_NODES + 255) / 256, 256, 0, stream>>>(dinv);
    k_deg_count<<<(N_EDGES + 255) / 256, 256, 0, stream>>>(ei, mode, dinv);
    k_deg_rsqrt<<<(N_NODES + 255) / 256, 256, 0, stream>>>(dinv);

    // layer 1
    k_gemm1<<<N_NODES / 16, 256, 0, stream>>>(x, W1, hx);
    k_agg1_init<<<N_NODES * HID / 4 / 256, 256, 0, stream>>>(hx, dinv, b1, agg);
    k_scatter1<<<N_EDGES * 64 / 256, 256, 0, stream>>>(ei, mode, dinv, hx, agg);
    k_relu<<<N_NODES * HID / 4 / 256, 256, 0, stream>>>(agg);

    // layer 2 (hx2 reuses hx buffer)
    k_gemm2<<<N_NODES / 16, 256, 0, stream>>>(agg, W2, hx);
    k_out_init<<<N_NODES * NC / 4 / 256, 256, 0, stream>>>(hx, dinv, b2, out);
    k_scatter2<<<N_EDGES * 16 / 256, 256, 0, stream>>>(ei, mode, dinv, hx, out);

    k_logsoftmax<<<N_NODES / 4, 256, 0, stream>>>(out);
}

// Round 6
// 634.984 us; speedup vs baseline: 4.8759x; 4.8759x over previous
//
#include <hip/hip_runtime.h>
#include <cstdint>
#include <cstddef>

#define N_NODES 100000
#define N_EDGES 600000
#define F_IN    128
#define HID     256
#define NC      64
#define NB_SCAN 391            // ceil(N_NODES/256)

// ---------------- edge-index dtype detection -------------------------------
// Reference declares int64, but JAX without x64 silently yields int32.
// If the buffer is int64 (values < 2^31), every odd 32-bit word is 0.
__global__ void k_detect(const int* __restrict__ ei_words, int* __restrict__ mode) {
    if (blockIdx.x == 0 && threadIdx.x == 0) {
        int allz = 1;
        for (int i = 0; i < 64; ++i) {
            long long s = (long long)i * (N_EDGES - 1) / 63;
            if (ei_words[2 * s + 1] != 0) { allz = 0; break; }
        }
        *mode = allz;   // 1 => int64, 0 => int32
    }
}

__device__ __forceinline__ int load_idx(const void* ei, int m, long long i) {
    return m ? (int)((const long long*)ei)[i] : ((const int*)ei)[i];
}

// ---------------- zero-init (replaces hipMemsetAsync for capture safety) ---
__global__ void k_zero(int* __restrict__ p, int n) {
    int i = blockIdx.x * blockDim.x + threadIdx.x;
    if (i < n) p[i] = 0;
}

// ---------------- degree histogram -----------------------------------------
__global__ void k_hist(const void* __restrict__ ei, const int* __restrict__ mode,
                       int* __restrict__ deg) {
    int e = blockIdx.x * blockDim.x + threadIdx.x;
    if (e >= N_EDGES) return;
    int d = load_idx(ei, *mode, (long long)N_EDGES + e);
    atomicAdd(&deg[d], 1);
}

// ---------------- CSR row_ptr: 3-step block scan ---------------------------
__global__ void k_scanA(const int* __restrict__ deg, int* __restrict__ ptmp,
                        int* __restrict__ bsum) {
    __shared__ int sm[256];
    int i = blockIdx.x * 256 + threadIdx.x;
    int v = (i < N_NODES) ? deg[i] : 0;
    sm[threadIdx.x] = v;
    __syncthreads();
    for (int off = 1; off < 256; off <<= 1) {
        int t = (threadIdx.x >= off) ? sm[threadIdx.x - off] : 0;
        __syncthreads();
        sm[threadIdx.x] += t;
        __syncthreads();
    }
    if (i < N_NODES) ptmp[i] = sm[threadIdx.x] - v;     // exclusive within block
    if (threadIdx.x == 255) bsum[blockIdx.x] = sm[255];
}

__global__ void k_scanB(int* __restrict__ bsum) {       // exclusive scan, NB<=512
    __shared__ int sm[512];
    int i = threadIdx.x;
    int v = (i < NB_SCAN) ? bsum[i] : 0;
    sm[i] = v;
    __syncthreads();
    for (int off = 1; off < 512; off <<= 1) {
        int t = (i >= off) ? sm[i - off] : 0;
        __syncthreads();
        sm[i] += t;
        __syncthreads();
    }
    if (i < NB_SCAN) bsum[i] = sm[i] - v;
}

__global__ void k_scanC(const int* __restrict__ deg, const int* __restrict__ ptmp,
                        const int* __restrict__ bsum, int* __restrict__ row_ptr,
                        int* __restrict__ cursor, float* __restrict__ dinv) {
    int i = blockIdx.x * 256 + threadIdx.x;
    if (i < N_NODES) {
        int rp = ptmp[i] + bsum[blockIdx.x];
        row_ptr[i] = rp;
        cursor[i]  = rp;
        dinv[i]    = rsqrtf(1.0f + (float)deg[i]);      // self-loop degree
    }
    if (i == 0) row_ptr[N_NODES] = N_EDGES;
}

// ---------------- CSR fill (order nondeterministic; fp-tolerant) -----------
__global__ void k_fill(const void* __restrict__ ei, const int* __restrict__ mode,
                       int* __restrict__ cursor, int* __restrict__ csr_src) {
    int e = blockIdx.x * blockDim.x + threadIdx.x;
    if (e >= N_EDGES) return;
    int m = *mode;
    int s = load_idx(ei, m, e);
    int d = load_idx(ei, m, (long long)N_EDGES + e);
    int pos = atomicAdd(&cursor[d], 1);
    csr_src[pos] = s;
}

// ---------------- layer-1 propagation: px = P x  (128 feats) ---------------
// px[n] = dinv[n] * ( sum_e dinv[src] * x[src] + dinv[n] * x[n] )
__global__ void k_gather1(const float* __restrict__ x, const int* __restrict__ row_ptr,
                          const int* __restrict__ csr_src, const float* __restrict__ dinv,
                          float* __restrict__ px) {
    int g = threadIdx.x >> 5;        // 8 nodes / block
    int j = threadIdx.x & 31;        // 32 lanes * float4 = 128 feats
    int n = blockIdx.x * 8 + g;
    float dn = dinv[n];
    const float4* xr = (const float4*)x;
    float4 a = xr[(size_t)n * 32 + j];
    float4 acc;
    acc.x = a.x * dn; acc.y = a.y * dn; acc.z = a.z * dn; acc.w = a.w * dn;
    int e0 = row_ptr[n], e1 = row_ptr[n + 1];
    for (int k = e0; k < e1; ++k) {
        int s = csr_src[k];          // broadcast across 32 lanes
        float w = dinv[s];
        float4 v = xr[(size_t)s * 32 + j];
        acc.x = fmaf(v.x, w, acc.x); acc.y = fmaf(v.y, w, acc.y);
        acc.z = fmaf(v.z, w, acc.z); acc.w = fmaf(v.w, w, acc.w);
    }
    float4 o;
    o.x = acc.x * dn; o.y = acc.y * dn; o.z = acc.z * dn; o.w = acc.w * dn;
    ((float4*)px)[(size_t)n * 32 + j] = o;
}

// ---------------- GEMM1 + bias + ReLU: h = relu(px @ W1 + b1) --------------
__global__ void k_gemm1(const float* __restrict__ px, const float* __restrict__ W1,
                        const float* __restrict__ b1, float* __restrict__ h) {
    const int col  = threadIdx.x;
    const int row0 = blockIdx.x * 16;
    float acc[16];
#pragma unroll
    for (int r = 0; r < 16; ++r) acc[r] = 0.0f;
    for (int k = 0; k < F_IN; ++k) {
        const float w = W1[k * HID + col];
#pragma unroll
        for (int r = 0; r < 16; ++r)
            acc[r] = fmaf(px[(size_t)(row0 + r) * F_IN + k], w, acc[r]);
    }
    const float bb = b1[col];
#pragma unroll
    for (int r = 0; r < 16; ++r)
        h[(size_t)(row0 + r) * HID + col] = fmaxf(acc[r] + bb, 0.0f);
}

// ---------------- GEMM2: hx2 = h @ W2  (bias applied after propagation) ----
__global__ void k_gemm2(const float* __restrict__ h, const float* __restrict__ W2,
                        float* __restrict__ hx2) {
    const int c = threadIdx.x & 63;
    const int g = threadIdx.x >> 6;
    const int row0 = blockIdx.x * 16 + g * 4;
    float acc[4] = {0.f, 0.f, 0.f, 0.f};
    for (int k = 0; k < HID; ++k) {
        const float w = W2[k * NC + c];
#pragma unroll
        for (int r = 0; r < 4; ++r)
            acc[r] = fmaf(h[(size_t)(row0 + r) * HID + k], w, acc[r]);
    }
#pragma unroll
    for (int r = 0; r < 4; ++r)
        hx2[(size_t)(row0 + r) * NC + c] = acc[r];
}

// ---------------- layer-2 propagation + bias + log_softmax -----------------
// out[n] = logsoftmax( dinv[n]*(sum dinv[s]*hx2[s] + dinv[n]*hx2[n]) + b2 )
__global__ void k_gather2sm(const float* __restrict__ hx2, const int* __restrict__ row_ptr,
                            const int* __restrict__ csr_src, const float* __restrict__ dinv,
                            const float* __restrict__ b2, float* __restrict__ out) {
    int g = threadIdx.x >> 4;        // 16 nodes / block
    int j = threadIdx.x & 15;        // 16 lanes * float4 = 64 classes
    int n = blockIdx.x * 16 + g;
    float dn = dinv[n];
    const float4* hr = (const float4*)hx2;
    float4 a = hr[(size_t)n * 16 + j];
    float4 acc;
    acc.x = a.x * dn; acc.y = a.y * dn; acc.z = a.z * dn; acc.w = a.w * dn;
    int e0 = row_ptr[n], e1 = row_ptr[n + 1];
    for (int k = e0; k < e1; ++k) {
        int s = csr_src[k];
        float w = dinv[s];
        float4 v = hr[(size_t)s * 16 + j];
        acc.x = fmaf(v.x, w, acc.x); acc.y = fmaf(v.y, w, acc.y);
        acc.z = fmaf(v.z, w, acc.z); acc.w = fmaf(v.w, w, acc.w);
    }
    const float4 b = ((const float4*)b2)[j];
    float4 o;
    o.x = fmaf(acc.x, dn, b.x); o.y = fmaf(acc.y, dn, b.y);
    o.z = fmaf(acc.z, dn, b.z); o.w = fmaf(acc.w, dn, b.w);
    // log_softmax across the 16 lanes of this node (xor masks stay in-group)
    float mx = fmaxf(fmaxf(o.x, o.y), fmaxf(o.z, o.w));
#pragma unroll
    for (int msk = 8; msk; msk >>= 1) mx = fmaxf(mx, __shfl_xor(mx, msk));
    float s4 = expf(o.x - mx) + expf(o.y - mx) + expf(o.z - mx) + expf(o.w - mx);
#pragma unroll
    for (int msk = 8; msk; msk >>= 1) s4 += __shfl_xor(s4, msk);
    float ls = mx + logf(s4);
    o.x -= ls; o.y -= ls; o.z -= ls; o.w -= ls;
    ((float4*)out)[(size_t)n * 16 + j] = o;
}

// ---------------- launch ----------------------------------------------------
extern "C" void kernel_launch(void* const* d_in, const int* in_sizes, int n_in,
                              void* d_out, int out_size, void* d_ws, size_t ws_size,
                              hipStream_t stream) {
    const float* x  = (const float*)d_in[0];
    const float* W1 = (const float*)d_in[1];
    const float* b1 = (const float*)d_in[2];
    const float* W2 = (const float*)d_in[3];
    const float* b2 = (const float*)d_in[4];
    const void*  ei = d_in[5];
    float* out = (float*)d_out;

    char* ws = (char*)d_ws;
    size_t off = 0;
    auto alloc = [&](size_t bytes) {
        char* p = ws + off;
        off += (bytes + 255) & ~(size_t)255;
        return p;
    };
    int*   mode    = (int*)  alloc(4);
    int*   deg     = (int*)  alloc((size_t)N_NODES * 4);
    int*   ptmp    = (int*)  alloc((size_t)N_NODES * 4);
    int*   bsum    = (int*)  alloc(4096);
    int*   row_ptr = (int*)  alloc((size_t)(N_NODES + 1) * 4);
    int*   cursor  = (int*)  alloc((size_t)N_NODES * 4);
    float* dinv    = (float*)alloc((size_t)N_NODES * 4);
    int*   csr_src = (int*)  alloc((size_t)N_EDGES * 4);
    float* px      = (float*)alloc((size_t)N_NODES * F_IN * 4);
    float* h       = (float*)alloc((size_t)N_NODES * HID * 4);
    float* hx2     = (float*)alloc((size_t)N_NODES * NC * 4);

    k_detect<<<1, 64, 0, stream>>>((const int*)ei, mode);

    k_zero<<<(N_NODES + 255) / 256, 256, 0, stream>>>(deg, N_NODES);
    k_hist<<<(N_EDGES + 255) / 256, 256, 0, stream>>>(ei, mode, deg);
    k_scanA<<<NB_SCAN, 256, 0, stream>>>(deg, ptmp, bsum);
    k_scanB<<<1, 512, 0, stream>>>(bsum);
    k_scanC<<<NB_SCAN, 256, 0, stream>>>(deg, ptmp, bsum, row_ptr, cursor, dinv);
    k_fill<<<(N_EDGES + 255) / 256, 256, 0, stream>>>(ei, mode, cursor, csr_src);

    // layer 1: propagate x, then GEMM+bias+relu
    k_gather1<<<N_NODES / 8, 256, 0, stream>>>(x, row_ptr, csr_src, dinv, px);
    k_gemm1<<<N_NODES / 16, 256, 0, stream>>>(px, W1, b1, h);

    // layer 2: GEMM, then propagate + bias + log_softmax
    k_gemm2<<<N_NODES / 16, 256, 0, stream>>>(h, W2, hx2);
    k_gather2sm<<<N_NODES / 16, 256, 0, stream>>>(hx2, row_ptr, csr_src, dinv, b2, out);
}

// Round 9
// 273.120 us; speedup vs baseline: 11.3361x; 2.3249x over previous
//
#include <hip/hip_runtime.h>
#include <cstdint>
#include <cstddef>

#define N_NODES 100000
#define N_EDGES 600000
#define F_IN    128
#define HID     256
#define NC      64
#define NB_SCAN 391            // ceil(N_NODES/256)

typedef __attribute__((ext_vector_type(8))) short bf16x8;
typedef __attribute__((ext_vector_type(4))) float f32x4;

// fp32 -> bf16 round-to-nearest-even
__device__ __forceinline__ unsigned short f2bf(float f) {
    unsigned int u = __float_as_uint(f);
    u = (u + 0x7FFFu + ((u >> 16) & 1u)) >> 16;
    return (unsigned short)u;
}

// ---------------- edge-index dtype detection -------------------------------
// Reference declares int64, but JAX without x64 silently yields int32.
__global__ void k_detect(const int* __restrict__ ei_words, int* __restrict__ mode) {
    if (blockIdx.x == 0 && threadIdx.x == 0) {
        int allz = 1;
        for (int i = 0; i < 64; ++i) {
            long long s = (long long)i * (N_EDGES - 1) / 63;
            if (ei_words[2 * s + 1] != 0) { allz = 0; break; }
        }
        *mode = allz;   // 1 => int64, 0 => int32
    }
}

__device__ __forceinline__ int load_idx(const void* ei, int m, long long i) {
    return m ? (int)((const long long*)ei)[i] : ((const int*)ei)[i];
}

__global__ void k_zero(int* __restrict__ p, int n) {
    int i = blockIdx.x * blockDim.x + threadIdx.x;
    if (i < n) p[i] = 0;
}

// ---------------- degree histogram -----------------------------------------
__global__ void k_hist(const void* __restrict__ ei, const int* __restrict__ mode,
                       int* __restrict__ deg) {
    int e = blockIdx.x * blockDim.x + threadIdx.x;
    if (e >= N_EDGES) return;
    int d = load_idx(ei, *mode, (long long)N_EDGES + e);
    atomicAdd(&deg[d], 1);
}

// ---------------- CSR row_ptr: 3-step block scan ---------------------------
__global__ void k_scanA(const int* __restrict__ deg, int* __restrict__ ptmp,
                        int* __restrict__ bsum) {
    __shared__ int sm[256];
    int i = blockIdx.x * 256 + threadIdx.x;
    int v = (i < N_NODES) ? deg[i] : 0;
    sm[threadIdx.x] = v;
    __syncthreads();
    for (int off = 1; off < 256; off <<= 1) {
        int t = (threadIdx.x >= off) ? sm[threadIdx.x - off] : 0;
        __syncthreads();
        sm[threadIdx.x] += t;
        __syncthreads();
    }
    if (i < N_NODES) ptmp[i] = sm[threadIdx.x] - v;     // exclusive within block
    if (threadIdx.x == 255) bsum[blockIdx.x] = sm[255];
}

__global__ void k_scanB(int* __restrict__ bsum) {       // exclusive scan, NB<=512
    __shared__ int sm[512];
    int i = threadIdx.x;
    int v = (i < NB_SCAN) ? bsum[i] : 0;
    sm[i] = v;
    __syncthreads();
    for (int off = 1; off < 512; off <<= 1) {
        int t = (i >= off) ? sm[i - off] : 0;
        __syncthreads();
        sm[i] += t;
        __syncthreads();
    }
    if (i < NB_SCAN) bsum[i] = sm[i] - v;
}

__global__ void k_scanC(const int* __restrict__ deg, const int* __restrict__ ptmp,
                        const int* __restrict__ bsum, int* __restrict__ row_ptr,
                        int* __restrict__ cursor, float* __restrict__ dinv) {
    int i = blockIdx.x * 256 + threadIdx.x;
    if (i < N_NODES) {
        int rp = ptmp[i] + bsum[blockIdx.x];
        row_ptr[i] = rp;
        cursor[i]  = rp;
        dinv[i]    = rsqrtf(1.0f + (float)deg[i]);      // self-loop degree
    }
    if (i == 0) row_ptr[N_NODES] = N_EDGES;
}

// ---------------- CSR fill (order nondeterministic; fp-tolerant) -----------
__global__ void k_fill(const void* __restrict__ ei, const int* __restrict__ mode,
                       int* __restrict__ cursor, int* __restrict__ csr_src) {
    int e = blockIdx.x * blockDim.x + threadIdx.x;
    if (e >= N_EDGES) return;
    int m = *mode;
    int s = load_idx(ei, m, e);
    int d = load_idx(ei, m, (long long)N_EDGES + e);
    int pos = atomicAdd(&cursor[d], 1);
    csr_src[pos] = s;
}

// ---------------- weight transpose + bf16 convert --------------------------
__global__ void k_w1t(const float* __restrict__ W1, unsigned short* __restrict__ W1T) {
    int i = blockIdx.x * 256 + threadIdx.x;             // 128*256
    int k = i >> 8, n = i & 255;
    W1T[n * F_IN + k] = f2bf(W1[i]);
}
__global__ void k_w2t(const float* __restrict__ W2, unsigned short* __restrict__ W2T) {
    int i = blockIdx.x * 256 + threadIdx.x;             // 256*64
    int k = i >> 6, n = i & 63;
    W2T[n * HID + k] = f2bf(W2[i]);
}

// ---------------- layer-1 propagation: px = P x  (bf16 out) ----------------
__global__ void k_gather1(const float* __restrict__ x, const int* __restrict__ row_ptr,
                          const int* __restrict__ csr_src, const float* __restrict__ dinv,
                          unsigned short* __restrict__ px) {
    int g = threadIdx.x >> 5;        // 8 nodes / block
    int j = threadIdx.x & 31;        // 32 lanes * float4 = 128 feats
    int n = blockIdx.x * 8 + g;
    float dn = dinv[n];
    const float4* xr = (const float4*)x;
    float4 a = xr[(size_t)n * 32 + j];
    float4 acc;
    acc.x = a.x * dn; acc.y = a.y * dn; acc.z = a.z * dn; acc.w = a.w * dn;
    int e0 = row_ptr[n], e1 = row_ptr[n + 1];
    for (int k = e0; k < e1; ++k) {
        int s = csr_src[k];          // broadcast across 32 lanes
        float w = dinv[s];
        float4 v = xr[(size_t)s * 32 + j];
        acc.x = fmaf(v.x, w, acc.x); acc.y = fmaf(v.y, w, acc.y);
        acc.z = fmaf(v.z, w, acc.z); acc.w = fmaf(v.w, w, acc.w);
    }
    ushort4 o;
    o.x = f2bf(acc.x * dn); o.y = f2bf(acc.y * dn);
    o.z = f2bf(acc.z * dn); o.w = f2bf(acc.w * dn);
    *(ushort4*)(px + (size_t)n * F_IN + j * 4) = o;
}

// ---------------- GEMM1 (MFMA bf16): h = relu(px @ W1 + b1), bf16 out ------
// mfma(b_frag, a_frag, acc) => transposed D: lane&15 = output row offset,
// (lane>>4)*4 + reg = 4 consecutive output cols. 2 waves x 16 rows = 32 rows/block.
__global__ __launch_bounds__(128) void k_gemm1_mfma(
        const unsigned short* __restrict__ px, const unsigned short* __restrict__ W1T,
        const float* __restrict__ b1, unsigned short* __restrict__ h) {
    const int lane = threadIdx.x & 63;
    const int wid  = threadIdx.x >> 6;
    const int row0 = blockIdx.x * 32 + wid * 16;
    const int l15  = lane & 15, lhi = lane >> 4;

    bf16x8 a[4];
    const unsigned short* pa = px + (size_t)(row0 + l15) * F_IN + lhi * 8;
#pragma unroll
    for (int ks = 0; ks < 4; ++ks) a[ks] = *(const bf16x8*)(pa + ks * 32);

    f32x4 acc[16];
#pragma unroll
    for (int t = 0; t < 16; ++t) acc[t] = (f32x4){0.f, 0.f, 0.f, 0.f};

#pragma unroll
    for (int nt = 0; nt < 16; ++nt) {
        const unsigned short* pb = W1T + (size_t)(nt * 16 + l15) * F_IN + lhi * 8;
        bf16x8 b0 = *(const bf16x8*)(pb);
        bf16x8 bq = *(const bf16x8*)(pb + 32);
        bf16x8 b2 = *(const bf16x8*)(pb + 64);
        bf16x8 b3 = *(const bf16x8*)(pb + 96);
        acc[nt] = __builtin_amdgcn_mfma_f32_16x16x32_bf16(b0, a[0], acc[nt], 0, 0, 0);
        acc[nt] = __builtin_amdgcn_mfma_f32_16x16x32_bf16(bq, a[1], acc[nt], 0, 0, 0);
        acc[nt] = __builtin_amdgcn_mfma_f32_16x16x32_bf16(b2, a[2], acc[nt], 0, 0, 0);
        acc[nt] = __builtin_amdgcn_mfma_f32_16x16x32_bf16(b3, a[3], acc[nt], 0, 0, 0);
    }

    const int r = row0 + l15;
#pragma unroll
    for (int nt = 0; nt < 16; ++nt) {
        int c0 = nt * 16 + lhi * 4;
        float4 bb = *(const float4*)(b1 + c0);
        ushort4 o;
        o.x = f2bf(fmaxf(acc[nt][0] + bb.x, 0.f));
        o.y = f2bf(fmaxf(acc[nt][1] + bb.y, 0.f));
        o.z = f2bf(fmaxf(acc[nt][2] + bb.z, 0.f));
        o.w = f2bf(fmaxf(acc[nt][3] + bb.w, 0.f));
        *(ushort4*)(h + (size_t)r * HID + c0) = o;
    }
}

// ---------------- GEMM2 (MFMA bf16): hx2 = h @ W2 (fp32 out) ---------------
__global__ __launch_bounds__(128) void k_gemm2_mfma(
        const unsigned short* __restrict__ h, const unsigned short* __restrict__ W2T,
        float* __restrict__ hx2) {
    const int lane = threadIdx.x & 63;
    const int wid  = threadIdx.x >> 6;
    const int row0 = blockIdx.x * 32 + wid * 16;
    const int l15  = lane & 15, lhi = lane >> 4;

    bf16x8 a[8];
    const unsigned short* pa = h + (size_t)(row0 + l15) * HID + lhi * 8;
#pragma unroll
    for (int ks = 0; ks < 8; ++ks) a[ks] = *(const bf16x8*)(pa + ks * 32);

    f32x4 acc[4];
#pragma unroll
    for (int t = 0; t < 4; ++t) acc[t] = (f32x4){0.f, 0.f, 0.f, 0.f};

#pragma unroll
    for (int nt = 0; nt < 4; ++nt) {
        const unsigned short* pb = W2T + (size_t)(nt * 16 + l15) * HID + lhi * 8;
#pragma unroll
        for (int ks = 0; ks < 8; ++ks) {
            bf16x8 b = *(const bf16x8*)(pb + ks * 32);
            acc[nt] = __builtin_amdgcn_mfma_f32_16x16x32_bf16(b, a[ks], acc[nt], 0, 0, 0);
        }
    }

    const int r = row0 + l15;
#pragma unroll
    for (int nt = 0; nt < 4; ++nt) {
        int c0 = nt * 16 + lhi * 4;
        float4 o = make_float4(acc[nt][0], acc[nt][1], acc[nt][2], acc[nt][3]);
        *(float4*)(hx2 + (size_t)r * NC + c0) = o;
    }
}

// ---------------- layer-2 propagation + bias + log_softmax -----------------
__global__ void k_gather2sm(const float* __restrict__ hx2, const int* __restrict__ row_ptr,
                            const int* __restrict__ csr_src, const float* __restrict__ dinv,
                            const float* __restrict__ b2, float* __restrict__ out) {
    int g = threadIdx.x >> 4;        // 16 nodes / block
    int j = threadIdx.x & 15;        // 16 lanes * float4 = 64 classes
    int n = blockIdx.x * 16 + g;
    float dn = dinv[n];
    const float4* hr = (const float4*)hx2;
    float4 a = hr[(size_t)n * 16 + j];
    float4 acc;
    acc.x = a.x * dn; acc.y = a.y * dn; acc.z = a.z * dn; acc.w = a.w * dn;
    int e0 = row_ptr[n], e1 = row_ptr[n + 1];
    for (int k = e0; k < e1; ++k) {
        int s = csr_src[k];
        float w = dinv[s];
        float4 v = hr[(size_t)s * 16 + j];
        acc.x = fmaf(v.x, w, acc.x); acc.y = fmaf(v.y, w, acc.y);
        acc.z = fmaf(v.z, w, acc.z); acc.w = fmaf(v.w, w, acc.w);
    }
    const float4 b = ((const float4*)b2)[j];
    float4 o;
    o.x = fmaf(acc.x, dn, b.x); o.y = fmaf(acc.y, dn, b.y);
    o.z = fmaf(acc.z, dn, b.z); o.w = fmaf(acc.w, dn, b.w);
    float mx = fmaxf(fmaxf(o.x, o.y), fmaxf(o.z, o.w));
#pragma unroll
    for (int msk = 8; msk; msk >>= 1) mx = fmaxf(mx, __shfl_xor(mx, msk));
    float s4 = expf(o.x - mx) + expf(o.y - mx) + expf(o.z - mx) + expf(o.w - mx);
#pragma unroll
    for (int msk = 8; msk; msk >>= 1) s4 += __shfl_xor(s4, msk);
    float ls = mx + logf(s4);
    o.x -= ls; o.y -= ls; o.z -= ls; o.w -= ls;
    ((float4*)out)[(size_t)n * 16 + j] = o;
}

// ---------------- launch ----------------------------------------------------
extern "C" void kernel_launch(void* const* d_in, const int* in_sizes, int n_in,
                              void* d_out, int out_size, void* d_ws, size_t ws_size,
                              hipStream_t stream) {
    const float* x  = (const float*)d_in[0];
    const float* W1 = (const float*)d_in[1];
    const float* b1 = (const float*)d_in[2];
    const float* W2 = (const float*)d_in[3];
    const float* b2 = (const float*)d_in[4];
    const void*  ei = d_in[5];
    float* out = (float*)d_out;

    char* ws = (char*)d_ws;
    size_t off = 0;
    auto alloc = [&](size_t bytes) {
        char* p = ws + off;
        off += (bytes + 255) & ~(size_t)255;
        return p;
    };
    int*            mode    = (int*)            alloc(4);
    int*            deg     = (int*)            alloc((size_t)N_NODES * 4);
    int*            ptmp    = (int*)            alloc((size_t)N_NODES * 4);
    int*            bsum    = (int*)            alloc(4096);
    int*            row_ptr = (int*)            alloc((size_t)(N_NODES + 1) * 4);
    int*            cursor  = (int*)            alloc((size_t)N_NODES * 4);
    float*          dinv    = (float*)          alloc((size_t)N_NODES * 4);
    int*            csr_src = (int*)            alloc((size_t)N_EDGES * 4);
    unsigned short* W1T     = (unsigned short*) alloc((size_t)F_IN * HID * 2);
    unsigned short* W2T     = (unsigned short*) alloc((size_t)HID * NC * 2);
    unsigned short* px      = (unsigned short*) alloc((size_t)N_NODES * F_IN * 2);
    unsigned short* h       = (unsigned short*) alloc((size_t)N_NODES * HID * 2);
    float*          hx2     = (float*)          alloc((size_t)N_NODES * NC * 4);

    k_detect<<<1, 64, 0, stream>>>((const int*)ei, mode);

    k_zero<<<(N_NODES + 255) / 256, 256, 0, stream>>>(deg, N_NODES);
    k_hist<<<(N_EDGES + 255) / 256, 256, 0, stream>>>(ei, mode, deg);
    k_scanA<<<NB_SCAN, 256, 0, stream>>>(deg, ptmp, bsum);
    k_scanB<<<1, 512, 0, stream>>>(bsum);
    k_scanC<<<NB_SCAN, 256, 0, stream>>>(deg, ptmp, bsum, row_ptr, cursor, dinv);
    k_fill<<<(N_EDGES + 255) / 256, 256, 0, stream>>>(ei, mode, cursor, csr_src);

    // weight prep (tiny)
    k_w1t<<<F_IN * HID / 256, 256, 0, stream>>>(W1, W1T);
    k_w2t<<<HID * NC / 256, 256, 0, stream>>>(W2, W2T);

    // layer 1: propagate x (bf16 out), then MFMA GEMM + bias + relu (bf16 out)
    k_gather1<<<N_NODES / 8, 256, 0, stream>>>(x, row_ptr, csr_src, dinv, px);
    k_gemm1_mfma<<<N_NODES / 32, 128, 0, stream>>>(px, W1T, b1, h);

    // layer 2: MFMA GEMM (fp32 out), then propagate + bias + log_softmax
    k_gemm2_mfma<<<N_NODES / 32, 128, 0, stream>>>(h, W2T, hx2);
    k_gather2sm<<<N_NODES / 16, 256, 0, stream>>>(hx2, row_ptr, csr_src, dinv, b2, out);
}

// Round 10
// 227.184 us; speedup vs baseline: 13.6282x; 1.2022x over previous
//
#include <hip/hip_runtime.h>
#include <cstdint>
#include <cstddef>

#define N_NODES 100000
#define N_EDGES 600000
#define F_IN    128
#define HID     256
#define NC      64
#define NB_SCAN 391            // ceil(N_NODES/256)

typedef __attribute__((ext_vector_type(8))) short bf16x8;
typedef __attribute__((ext_vector_type(4))) float f32x4;

// fp32 -> bf16 round-to-nearest-even
__device__ __forceinline__ unsigned short f2bf(float f) {
    unsigned int u = __float_as_uint(f);
    u = (u + 0x7FFFu + ((u >> 16) & 1u)) >> 16;
    return (unsigned short)u;
}
__device__ __forceinline__ float bf2f(unsigned short u) {
    return __uint_as_float(((unsigned int)u) << 16);
}

// ---------------- edge-index dtype detection -------------------------------
// Reference declares int64, but JAX without x64 silently yields int32.
__global__ void k_detect(const int* __restrict__ ei_words, int* __restrict__ mode) {
    if (blockIdx.x == 0 && threadIdx.x == 0) {
        int allz = 1;
        for (int i = 0; i < 64; ++i) {
            long long s = (long long)i * (N_EDGES - 1) / 63;
            if (ei_words[2 * s + 1] != 0) { allz = 0; break; }
        }
        *mode = allz;   // 1 => int64, 0 => int32
    }
}

__device__ __forceinline__ int load_idx(const void* ei, int m, long long i) {
    return m ? (int)((const long long*)ei)[i] : ((const int*)ei)[i];
}

__global__ void k_zero(int* __restrict__ p, int n) {
    int i = blockIdx.x * blockDim.x + threadIdx.x;
    if (i < n) p[i] = 0;
}

// ---------------- degree histogram -----------------------------------------
__global__ void k_hist(const void* __restrict__ ei, const int* __restrict__ mode,
                       int* __restrict__ deg) {
    int e = blockIdx.x * blockDim.x + threadIdx.x;
    if (e >= N_EDGES) return;
    int d = load_idx(ei, *mode, (long long)N_EDGES + e);
    atomicAdd(&deg[d], 1);
}

// ---------------- CSR row_ptr: 3-step block scan ---------------------------
__global__ void k_scanA(const int* __restrict__ deg, int* __restrict__ ptmp,
                        int* __restrict__ bsum) {
    __shared__ int sm[256];
    int i = blockIdx.x * 256 + threadIdx.x;
    int v = (i < N_NODES) ? deg[i] : 0;
    sm[threadIdx.x] = v;
    __syncthreads();
    for (int off = 1; off < 256; off <<= 1) {
        int t = (threadIdx.x >= off) ? sm[threadIdx.x - off] : 0;
        __syncthreads();
        sm[threadIdx.x] += t;
        __syncthreads();
    }
    if (i < N_NODES) ptmp[i] = sm[threadIdx.x] - v;     // exclusive within block
    if (threadIdx.x == 255) bsum[blockIdx.x] = sm[255];
}

__global__ void k_scanB(int* __restrict__ bsum) {       // exclusive scan, NB<=512
    __shared__ int sm[512];
    int i = threadIdx.x;
    int v = (i < NB_SCAN) ? bsum[i] : 0;
    sm[i] = v;
    __syncthreads();
    for (int off = 1; off < 512; off <<= 1) {
        int t = (i >= off) ? sm[i - off] : 0;
        __syncthreads();
        sm[i] += t;
        __syncthreads();
    }
    if (i < NB_SCAN) bsum[i] = sm[i] - v;
}

__global__ void k_scanC(const int* __restrict__ deg, const int* __restrict__ ptmp,
                        const int* __restrict__ bsum, int* __restrict__ row_ptr,
                        int* __restrict__ cursor, float* __restrict__ dinv) {
    int i = blockIdx.x * 256 + threadIdx.x;
    if (i < N_NODES) {
        int rp = ptmp[i] + bsum[blockIdx.x];
        row_ptr[i] = rp;
        cursor[i]  = rp;
        dinv[i]    = rsqrtf(1.0f + (float)deg[i]);      // self-loop degree
    }
    if (i == 0) row_ptr[N_NODES] = N_EDGES;
}

// ---------------- CSR fill (order nondeterministic; fp-tolerant) -----------
__global__ void k_fill(const void* __restrict__ ei, const int* __restrict__ mode,
                       int* __restrict__ cursor, int* __restrict__ csr_src) {
    int e = blockIdx.x * blockDim.x + threadIdx.x;
    if (e >= N_EDGES) return;
    int m = *mode;
    int s = load_idx(ei, m, e);
    int d = load_idx(ei, m, (long long)N_EDGES + e);
    int pos = atomicAdd(&cursor[d], 1);
    csr_src[pos] = s;
}

// ---------------- weight transpose + bf16 convert --------------------------
__global__ void k_w1t(const float* __restrict__ W1, unsigned short* __restrict__ W1T) {
    int i = blockIdx.x * 256 + threadIdx.x;             // 128*256
    int k = i >> 8, n = i & 255;
    W1T[n * F_IN + k] = f2bf(W1[i]);
}
__global__ void k_w2t(const float* __restrict__ W2, unsigned short* __restrict__ W2T) {
    int i = blockIdx.x * 256 + threadIdx.x;             // 256*64
    int k = i >> 6, n = i & 63;
    W2T[n * HID + k] = f2bf(W2[i]);
}

// ---------------- x -> bf16 (halves gather read traffic) -------------------
__global__ void k_xbf(const float* __restrict__ x, unsigned short* __restrict__ xbf) {
    int i = blockIdx.x * 256 + threadIdx.x;             // N*F_IN/8 threads
    const float4* xr = (const float4*)x;
    float4 a = xr[(size_t)i * 2];
    float4 b = xr[(size_t)i * 2 + 1];
    bf16x8 o;
    o[0] = (short)f2bf(a.x); o[1] = (short)f2bf(a.y);
    o[2] = (short)f2bf(a.z); o[3] = (short)f2bf(a.w);
    o[4] = (short)f2bf(b.x); o[5] = (short)f2bf(b.y);
    o[6] = (short)f2bf(b.z); o[7] = (short)f2bf(b.w);
    *(bf16x8*)(xbf + (size_t)i * 8) = o;
}

// ---------------- layer-1 propagation: px = P x  (bf16 in/out) -------------
__global__ void k_gather1(const unsigned short* __restrict__ xbf,
                          const int* __restrict__ row_ptr,
                          const int* __restrict__ csr_src, const float* __restrict__ dinv,
                          unsigned short* __restrict__ px) {
    int g = threadIdx.x >> 4;        // 16 nodes / block
    int j = threadIdx.x & 15;        // 16 lanes * 8 bf16 = 128 feats
    int n = blockIdx.x * 16 + g;
    float dn = dinv[n];
    bf16x8 sv = *(const bf16x8*)(xbf + (size_t)n * F_IN + j * 8);
    float acc[8];
#pragma unroll
    for (int t = 0; t < 8; ++t) acc[t] = bf2f((unsigned short)sv[t]) * dn;
    int e0 = row_ptr[n], e1 = row_ptr[n + 1];
    for (int k = e0; k < e1; ++k) {
        int s = csr_src[k];          // broadcast across the 16 lanes
        float w = dinv[s];
        bf16x8 v = *(const bf16x8*)(xbf + (size_t)s * F_IN + j * 8);
#pragma unroll
        for (int t = 0; t < 8; ++t)
            acc[t] = fmaf(bf2f((unsigned short)v[t]), w, acc[t]);
    }
    bf16x8 o;
#pragma unroll
    for (int t = 0; t < 8; ++t) o[t] = (short)f2bf(acc[t] * dn);
    *(bf16x8*)(px + (size_t)n * F_IN + j * 8) = o;
}

// ---------------- GEMM1 (MFMA bf16): h = relu(px @ W1 + b1), bf16 out ------
// Wave tile 64 rows x 64 cols: acc[4][4], B-frag reused across 4 M-tiles.
// mfma(b, a, acc) => D^T layout: row = row0+mt*16+(lane&15),
// cols = col0+nt*16+(lane>>4)*4 + reg  (validated rounds 6-9).
__global__ __launch_bounds__(256) void k_gemm1_mfma(
        const unsigned short* __restrict__ px, const unsigned short* __restrict__ W1T,
        const float* __restrict__ b1, unsigned short* __restrict__ h) {
    const int lane = threadIdx.x & 63;
    const int w    = threadIdx.x >> 6;          // 4 waves: col slices
    const int l15  = lane & 15, lhi = lane >> 4;
    const int row0 = blockIdx.x * 64;
    const int col0 = w * 64;

    f32x4 acc[4][4];
#pragma unroll
    for (int mt = 0; mt < 4; ++mt)
#pragma unroll
        for (int nt = 0; nt < 4; ++nt) acc[mt][nt] = (f32x4){0.f, 0.f, 0.f, 0.f};

#pragma unroll
    for (int ks = 0; ks < 4; ++ks) {
        bf16x8 a[4];
#pragma unroll
        for (int mt = 0; mt < 4; ++mt)
            a[mt] = *(const bf16x8*)(px + (size_t)(row0 + mt * 16 + l15) * F_IN + ks * 32 + lhi * 8);
#pragma unroll
        for (int nt = 0; nt < 4; ++nt) {
            bf16x8 b = *(const bf16x8*)(W1T + (size_t)(col0 + nt * 16 + l15) * F_IN + ks * 32 + lhi * 8);
#pragma unroll
            for (int mt = 0; mt < 4; ++mt)
                acc[mt][nt] = __builtin_amdgcn_mfma_f32_16x16x32_bf16(b, a[mt], acc[mt][nt], 0, 0, 0);
        }
    }

#pragma unroll
    for (int mt = 0; mt < 4; ++mt) {
        const int r = row0 + mt * 16 + l15;
        if (r < N_NODES) {
#pragma unroll
            for (int nt = 0; nt < 4; ++nt) {
                int c0 = col0 + nt * 16 + lhi * 4;
                float4 bb = *(const float4*)(b1 + c0);
                ushort4 o;
                o.x = f2bf(fmaxf(acc[mt][nt][0] + bb.x, 0.f));
                o.y = f2bf(fmaxf(acc[mt][nt][1] + bb.y, 0.f));
                o.z = f2bf(fmaxf(acc[mt][nt][2] + bb.z, 0.f));
                o.w = f2bf(fmaxf(acc[mt][nt][3] + bb.w, 0.f));
                *(ushort4*)(h + (size_t)r * HID + c0) = o;
            }
        }
    }
}

// ---------------- GEMM2 (MFMA bf16): hx2 = h @ W2 (fp32 out) ---------------
// Wave tile 64 rows x 64 cols (all of N); block = 4 waves x 64 rows = 256 rows.
__global__ __launch_bounds__(256) void k_gemm2_mfma(
        const unsigned short* __restrict__ h, const unsigned short* __restrict__ W2T,
        float* __restrict__ hx2) {
    const int lane = threadIdx.x & 63;
    const int w    = threadIdx.x >> 6;
    const int l15  = lane & 15, lhi = lane >> 4;
    const int row0 = blockIdx.x * 256 + w * 64;

    f32x4 acc[4][4];
#pragma unroll
    for (int mt = 0; mt < 4; ++mt)
#pragma unroll
        for (int nt = 0; nt < 4; ++nt) acc[mt][nt] = (f32x4){0.f, 0.f, 0.f, 0.f};

#pragma unroll
    for (int ks = 0; ks < 8; ++ks) {
        bf16x8 a[4];
#pragma unroll
        for (int mt = 0; mt < 4; ++mt)
            a[mt] = *(const bf16x8*)(h + (size_t)(row0 + mt * 16 + l15) * HID + ks * 32 + lhi * 8);
#pragma unroll
        for (int nt = 0; nt < 4; ++nt) {
            bf16x8 b = *(const bf16x8*)(W2T + (size_t)(nt * 16 + l15) * HID + ks * 32 + lhi * 8);
#pragma unroll
            for (int mt = 0; mt < 4; ++mt)
                acc[mt][nt] = __builtin_amdgcn_mfma_f32_16x16x32_bf16(b, a[mt], acc[mt][nt], 0, 0, 0);
        }
    }

#pragma unroll
    for (int mt = 0; mt < 4; ++mt) {
        const int r = row0 + mt * 16 + l15;
        if (r < N_NODES) {
#pragma unroll
            for (int nt = 0; nt < 4; ++nt) {
                int c0 = nt * 16 + lhi * 4;
                float4 o = make_float4(acc[mt][nt][0], acc[mt][nt][1],
                                       acc[mt][nt][2], acc[mt][nt][3]);
                *(float4*)(hx2 + (size_t)r * NC + c0) = o;
            }
        }
    }
}

// ---------------- layer-2 propagation + bias + log_softmax -----------------
__global__ void k_gather2sm(const float* __restrict__ hx2, const int* __restrict__ row_ptr,
                            const int* __restrict__ csr_src, const float* __restrict__ dinv,
                            const float* __restrict__ b2, float* __restrict__ out) {
    int g = threadIdx.x >> 4;        // 16 nodes / block
    int j = threadIdx.x & 15;        // 16 lanes * float4 = 64 classes
    int n = blockIdx.x * 16 + g;
    float dn = dinv[n];
    const float4* hr = (const float4*)hx2;
    float4 a = hr[(size_t)n * 16 + j];
    float4 acc;
    acc.x = a.x * dn; acc.y = a.y * dn; acc.z = a.z * dn; acc.w = a.w * dn;
    int e0 = row_ptr[n], e1 = row_ptr[n + 1];
    for (int k = e0; k < e1; ++k) {
        int s = csr_src[k];
        float w = dinv[s];
        float4 v = hr[(size_t)s * 16 + j];
        acc.x = fmaf(v.x, w, acc.x); acc.y = fmaf(v.y, w, acc.y);
        acc.z = fmaf(v.z, w, acc.z); acc.w = fmaf(v.w, w, acc.w);
    }
    const float4 b = ((const float4*)b2)[j];
    float4 o;
    o.x = fmaf(acc.x, dn, b.x); o.y = fmaf(acc.y, dn, b.y);
    o.z = fmaf(acc.z, dn, b.z); o.w = fmaf(acc.w, dn, b.w);
    float mx = fmaxf(fmaxf(o.x, o.y), fmaxf(o.z, o.w));
#pragma unroll
    for (int msk = 8; msk; msk >>= 1) mx = fmaxf(mx, __shfl_xor(mx, msk));
    float s4 = expf(o.x - mx) + expf(o.y - mx) + expf(o.z - mx) + expf(o.w - mx);
#pragma unroll
    for (int msk = 8; msk; msk >>= 1) s4 += __shfl_xor(s4, msk);
    float ls = mx + logf(s4);
    o.x -= ls; o.y -= ls; o.z -= ls; o.w -= ls;
    ((float4*)out)[(size_t)n * 16 + j] = o;
}

// ---------------- launch ----------------------------------------------------
extern "C" void kernel_launch(void* const* d_in, const int* in_sizes, int n_in,
                              void* d_out, int out_size, void* d_ws, size_t ws_size,
                              hipStream_t stream) {
    const float* x  = (const float*)d_in[0];
    const float* W1 = (const float*)d_in[1];
    const float* b1 = (const float*)d_in[2];
    const float* W2 = (const float*)d_in[3];
    const float* b2 = (const float*)d_in[4];
    const void*  ei = d_in[5];
    float* out = (float*)d_out;

    char* ws = (char*)d_ws;
    size_t off = 0;
    auto alloc = [&](size_t bytes) {
        char* p = ws + off;
        off += (bytes + 255) & ~(size_t)255;
        return p;
    };
    int*            mode    = (int*)            alloc(4);
    int*            deg     = (int*)            alloc((size_t)N_NODES * 4);
    int*            ptmp    = (int*)            alloc((size_t)N_NODES * 4);
    int*            bsum    = (int*)            alloc(4096);
    int*            row_ptr = (int*)            alloc((size_t)(N_NODES + 1) * 4);
    int*            cursor  = (int*)            alloc((size_t)N_NODES * 4);
    float*          dinv    = (float*)          alloc((size_t)N_NODES * 4);
    int*            csr_src = (int*)            alloc((size_t)N_EDGES * 4);
    unsigned short* W1T     = (unsigned short*) alloc((size_t)F_IN * HID * 2);
    unsigned short* W2T     = (unsigned short*) alloc((size_t)HID * NC * 2);
    unsigned short* xbf     = (unsigned short*) alloc((size_t)N_NODES * F_IN * 2);
    unsigned short* px      = (unsigned short*) alloc((size_t)(N_NODES + 64) * F_IN * 2);   // +pad rows (gemm1 tail reads)
    unsigned short* h       = (unsigned short*) alloc((size_t)(N_NODES + 128) * HID * 2);   // +pad rows (gemm2 tail reads)
    float*          hx2     = (float*)          alloc((size_t)N_NODES * NC * 4);

    k_detect<<<1, 64, 0, stream>>>((const int*)ei, mode);

    k_zero<<<(N_NODES + 255) / 256, 256, 0, stream>>>(deg, N_NODES);
    k_hist<<<(N_EDGES + 255) / 256, 256, 0, stream>>>(ei, mode, deg);
    k_scanA<<<NB_SCAN, 256, 0, stream>>>(deg, ptmp, bsum);
    k_scanB<<<1, 512, 0, stream>>>(bsum);
    k_scanC<<<NB_SCAN, 256, 0, stream>>>(deg, ptmp, bsum, row_ptr, cursor, dinv);
    k_fill<<<(N_EDGES + 255) / 256, 256, 0, stream>>>(ei, mode, cursor, csr_src);

    // weight + input prep
    k_w1t<<<F_IN * HID / 256, 256, 0, stream>>>(W1, W1T);
    k_w2t<<<HID * NC / 256, 256, 0, stream>>>(W2, W2T);
    k_xbf<<<N_NODES * F_IN / 8 / 256, 256, 0, stream>>>(x, xbf);

    // layer 1: propagate x (bf16), then MFMA GEMM + bias + relu (bf16 out)
    k_gather1<<<N_NODES / 16, 256, 0, stream>>>(xbf, row_ptr, csr_src, dinv, px);
    k_gemm1_mfma<<<(N_NODES + 63) / 64, 256, 0, stream>>>(px, W1T, b1, h);

    // layer 2: MFMA GEMM (fp32 out), then propagate + bias + log_softmax
    k_gemm2_mfma<<<(N_NODES + 255) / 256, 256, 0, stream>>>(h, W2T, hx2);
    k_gather2sm<<<N_NODES / 16, 256, 0, stream>>>(hx2, row_ptr, csr_src, dinv, b2, out);
}

// Round 13
// 220.090 us; speedup vs baseline: 14.0675x; 1.0322x over previous
//
#include <hip/hip_runtime.h>
#include <cstdint>
#include <cstddef>

#define N_NODES 100000
#define N_EDGES 600000
#define F_IN    128
#define HID     256
#define NC      64
#define NB_SCAN 391            // ceil(N_NODES/256)

typedef __attribute__((ext_vector_type(8))) short bf16x8;
typedef __attribute__((ext_vector_type(4))) float f32x4;

// fp32 -> bf16 round-to-nearest-even
__device__ __forceinline__ unsigned short f2bf(float f) {
    unsigned int u = __float_as_uint(f);
    u = (u + 0x7FFFu + ((u >> 16) & 1u)) >> 16;
    return (unsigned short)u;
}
__device__ __forceinline__ float bf2f(unsigned short u) {
    return __uint_as_float(((unsigned int)u) << 16);
}

// ---------------- edge-index dtype detection -------------------------------
// Reference declares int64, but JAX without x64 silently yields int32.
__global__ void k_detect(const int* __restrict__ ei_words, int* __restrict__ mode) {
    if (blockIdx.x == 0 && threadIdx.x == 0) {
        int allz = 1;
        for (int i = 0; i < 64; ++i) {
            long long s = (long long)i * (N_EDGES - 1) / 63;
            if (ei_words[2 * s + 1] != 0) { allz = 0; break; }
        }
        *mode = allz;   // 1 => int64, 0 => int32
    }
}

__device__ __forceinline__ int load_idx(const void* ei, int m, long long i) {
    return m ? (int)((const long long*)ei)[i] : ((const int*)ei)[i];
}

__global__ void k_zero(int* __restrict__ p, int n) {
    int i = blockIdx.x * blockDim.x + threadIdx.x;
    if (i < n) p[i] = 0;
}

// ---------------- degree histogram -----------------------------------------
__global__ void k_hist(const void* __restrict__ ei, const int* __restrict__ mode,
                       int* __restrict__ deg) {
    int e = blockIdx.x * blockDim.x + threadIdx.x;
    if (e >= N_EDGES) return;
    int d = load_idx(ei, *mode, (long long)N_EDGES + e);
    atomicAdd(&deg[d], 1);
}

// ---------------- CSR row_ptr: 3-step block scan ---------------------------
__global__ void k_scanA(const int* __restrict__ deg, int* __restrict__ ptmp,
                        int* __restrict__ bsum) {
    __shared__ int sm[256];
    int i = blockIdx.x * 256 + threadIdx.x;
    int v = (i < N_NODES) ? deg[i] : 0;
    sm[threadIdx.x] = v;
    __syncthreads();
    for (int off = 1; off < 256; off <<= 1) {
        int t = (threadIdx.x >= off) ? sm[threadIdx.x - off] : 0;
        __syncthreads();
        sm[threadIdx.x] += t;
        __syncthreads();
    }
    if (i < N_NODES) ptmp[i] = sm[threadIdx.x] - v;     // exclusive within block
    if (threadIdx.x == 255) bsum[blockIdx.x] = sm[255];
}

__global__ void k_scanB(int* __restrict__ bsum) {       // exclusive scan, NB<=512
    __shared__ int sm[512];
    int i = threadIdx.x;
    int v = (i < NB_SCAN) ? bsum[i] : 0;
    sm[i] = v;
    __syncthreads();
    for (int off = 1; off < 512; off <<= 1) {
        int t = (i >= off) ? sm[i - off] : 0;
        __syncthreads();
        sm[i] += t;
        __syncthreads();
    }
    if (i < NB_SCAN) bsum[i] = sm[i] - v;
}

__global__ void k_scanC(const int* __restrict__ deg, const int* __restrict__ ptmp,
                        const int* __restrict__ bsum, int* __restrict__ row_ptr,
                        int* __restrict__ cursor, float* __restrict__ dinv) {
    int i = blockIdx.x * 256 + threadIdx.x;
    if (i < N_NODES) {
        int rp = ptmp[i] + bsum[blockIdx.x];
        row_ptr[i] = rp;
        cursor[i]  = rp;
        dinv[i]    = rsqrtf(1.0f + (float)deg[i]);      // self-loop degree
    }
    if (i == 0) row_ptr[N_NODES] = N_EDGES;
}

// ---------------- CSR fill (order nondeterministic; fp-tolerant) -----------
__global__ void k_fill(const void* __restrict__ ei, const int* __restrict__ mode,
                       int* __restrict__ cursor, int* __restrict__ csr_src) {
    int e = blockIdx.x * blockDim.x + threadIdx.x;
    if (e >= N_EDGES) return;
    int m = *mode;
    int s = load_idx(ei, m, e);
    int d = load_idx(ei, m, (long long)N_EDGES + e);
    int pos = atomicAdd(&cursor[d], 1);
    csr_src[pos] = s;
}

// ---------------- weight transpose + bf16 convert --------------------------
__global__ void k_w1t(const float* __restrict__ W1, unsigned short* __restrict__ W1T) {
    int i = blockIdx.x * 256 + threadIdx.x;             // 128*256
    int k = i >> 8, n = i & 255;
    W1T[n * F_IN + k] = f2bf(W1[i]);
}
__global__ void k_w2t(const float* __restrict__ W2, unsigned short* __restrict__ W2T) {
    int i = blockIdx.x * 256 + threadIdx.x;             // 256*64
    int k = i >> 6, n = i & 63;
    W2T[n * HID + k] = f2bf(W2[i]);
}

// ---------------- x -> bf16 (halves gather read traffic) -------------------
__global__ void k_xbf(const float* __restrict__ x, unsigned short* __restrict__ xbf) {
    int i = blockIdx.x * 256 + threadIdx.x;             // N*F_IN/8 threads
    const float4* xr = (const float4*)x;
    float4 a = xr[(size_t)i * 2];
    float4 b = xr[(size_t)i * 2 + 1];
    bf16x8 o;
    o[0] = (short)f2bf(a.x); o[1] = (short)f2bf(a.y);
    o[2] = (short)f2bf(a.z); o[3] = (short)f2bf(a.w);
    o[4] = (short)f2bf(b.x); o[5] = (short)f2bf(b.y);
    o[6] = (short)f2bf(b.z); o[7] = (short)f2bf(b.w);
    *(bf16x8*)(xbf + (size_t)i * 8) = o;
}

// ---------------- layer-1 propagation: px = P x  (bf16 in/out) -------------
__global__ void k_gather1(const unsigned short* __restrict__ xbf,
                          const int* __restrict__ row_ptr,
                          const int* __restrict__ csr_src, const float* __restrict__ dinv,
                          unsigned short* __restrict__ px) {
    int g = threadIdx.x >> 4;        // 16 nodes / block
    int j = threadIdx.x & 15;        // 16 lanes * 8 bf16 = 128 feats
    int n = blockIdx.x * 16 + g;
    float dn = dinv[n];
    bf16x8 sv = *(const bf16x8*)(xbf + (size_t)n * F_IN + j * 8);
    float acc[8];
#pragma unroll
    for (int t = 0; t < 8; ++t) acc[t] = bf2f((unsigned short)sv[t]) * dn;
    int e0 = row_ptr[n], e1 = row_ptr[n + 1];
    for (int k = e0; k < e1; ++k) {
        int s = csr_src[k];          // broadcast across the 16 lanes
        float w = dinv[s];
        bf16x8 v = *(const bf16x8*)(xbf + (size_t)s * F_IN + j * 8);
#pragma unroll
        for (int t = 0; t < 8; ++t)
            acc[t] = fmaf(bf2f((unsigned short)v[t]), w, acc[t]);
    }
    bf16x8 o;
#pragma unroll
    for (int t = 0; t < 8; ++t) o[t] = (short)f2bf(acc[t] * dn);
    *(bf16x8*)(px + (size_t)n * F_IN + j * 8) = o;
}

// ---------------- fused MLP: hx2 = (relu(px@W1+b1)) @ W2, bf16 out ---------
// Phase A (per wave: 64 rows x 64-col slice, acc[4][4], validated layout):
//   h tile -> LDS (64x256 bf16, XOR-swizzled: byte ^= (row&7)<<4).
// Phase B (per wave: 16 rows x all 64 cols): K=256 from LDS, W2T from L2.
__global__ __launch_bounds__(256) void k_mlp_fused(
        const unsigned short* __restrict__ px, const unsigned short* __restrict__ W1T,
        const float* __restrict__ b1, const unsigned short* __restrict__ W2T,
        unsigned short* __restrict__ hx2) {
    __shared__ unsigned short hlds[64 * HID];           // 32 KB
    const int lane = threadIdx.x & 63;
    const int w    = threadIdx.x >> 6;                  // 4 waves
    const int l15  = lane & 15, lhi = lane >> 4;
    const int row0 = blockIdx.x * 64;

    // ---- phase A: gemm1 (rows row0..row0+63, cols w*64..w*64+63) ----
    {
        const int col0 = w * 64;
        f32x4 acc[4][4];
#pragma unroll
        for (int mt = 0; mt < 4; ++mt)
#pragma unroll
            for (int nt = 0; nt < 4; ++nt) acc[mt][nt] = (f32x4){0.f, 0.f, 0.f, 0.f};

#pragma unroll
        for (int ks = 0; ks < 4; ++ks) {
            bf16x8 a[4];
#pragma unroll
            for (int mt = 0; mt < 4; ++mt)
                a[mt] = *(const bf16x8*)(px + (size_t)(row0 + mt * 16 + l15) * F_IN + ks * 32 + lhi * 8);
#pragma unroll
            for (int nt = 0; nt < 4; ++nt) {
                bf16x8 b = *(const bf16x8*)(W1T + (size_t)(col0 + nt * 16 + l15) * F_IN + ks * 32 + lhi * 8);
#pragma unroll
                for (int mt = 0; mt < 4; ++mt)
                    acc[mt][nt] = __builtin_amdgcn_mfma_f32_16x16x32_bf16(b, a[mt], acc[mt][nt], 0, 0, 0);
            }
        }

        // epilogue: bias + relu -> bf16 -> swizzled LDS
#pragma unroll
        for (int mt = 0; mt < 4; ++mt) {
            const int lr = mt * 16 + l15;               // block-local row
#pragma unroll
            for (int nt = 0; nt < 4; ++nt) {
                int c0 = col0 + nt * 16 + lhi * 4;
                float4 bb = *(const float4*)(b1 + c0);
                ushort4 o;
                o.x = f2bf(fmaxf(acc[mt][nt][0] + bb.x, 0.f));
                o.y = f2bf(fmaxf(acc[mt][nt][1] + bb.y, 0.f));
                o.z = f2bf(fmaxf(acc[mt][nt][2] + bb.z, 0.f));
                o.w = f2bf(fmaxf(acc[mt][nt][3] + bb.w, 0.f));
                unsigned byte = (unsigned)(lr * (HID * 2) + c0 * 2) ^ ((lr & 7) << 4);
                *(ushort4*)((char*)hlds + byte) = o;
            }
        }
    }
    __syncthreads();

    // ---- phase B: gemm2 (wave w: rows w*16..w*16+15, all 64 cols) ----
    {
        const int lr = w * 16 + l15;                    // block-local row
        bf16x8 a2[8];
#pragma unroll
        for (int ks = 0; ks < 8; ++ks) {
            unsigned byte = (unsigned)(lr * (HID * 2) + ks * 64 + lhi * 16) ^ ((lr & 7) << 4);
            a2[ks] = *(const bf16x8*)((const char*)hlds + byte);
        }
        f32x4 acc2[4];
#pragma unroll
        for (int nt = 0; nt < 4; ++nt) acc2[nt] = (f32x4){0.f, 0.f, 0.f, 0.f};
#pragma unroll
        for (int nt = 0; nt < 4; ++nt) {
            const unsigned short* pb = W2T + (size_t)(nt * 16 + l15) * HID + lhi * 8;
#pragma unroll
            for (int ks = 0; ks < 8; ++ks) {
                bf16x8 b = *(const bf16x8*)(pb + ks * 32);
                acc2[nt] = __builtin_amdgcn_mfma_f32_16x16x32_bf16(b, a2[ks], acc2[nt], 0, 0, 0);
            }
        }
        const int r = row0 + lr;
        if (r < N_NODES) {
#pragma unroll
            for (int nt = 0; nt < 4; ++nt) {
                int c0 = nt * 16 + lhi * 4;
                ushort4 o;
                o.x = f2bf(acc2[nt][0]); o.y = f2bf(acc2[nt][1]);
                o.z = f2bf(acc2[nt][2]); o.w = f2bf(acc2[nt][3]);
                *(ushort4*)(hx2 + (size_t)r * NC + c0) = o;
            }
        }
    }
}

// ---------------- layer-2 propagation + bias + log_softmax -----------------
// hx2 is bf16 [N][64]; accumulate fp32, finish with log_softmax per node.
__global__ void k_gather2sm(const unsigned short* __restrict__ hx2,
                            const int* __restrict__ row_ptr,
                            const int* __restrict__ csr_src, const float* __restrict__ dinv,
                            const float* __restrict__ b2, float* __restrict__ out) {
    int g = threadIdx.x >> 4;        // 16 nodes / block
    int j = threadIdx.x & 15;        // 16 lanes * 4 = 64 classes
    int n = blockIdx.x * 16 + g;
    float dn = dinv[n];
    ushort4 sv = *(const ushort4*)(hx2 + (size_t)n * NC + j * 4);
    float ax = bf2f(sv.x) * dn, ay = bf2f(sv.y) * dn,
          az = bf2f(sv.z) * dn, aw = bf2f(sv.w) * dn;
    int e0 = row_ptr[n], e1 = row_ptr[n + 1];
    for (int k = e0; k < e1; ++k) {
        int s = csr_src[k];
        float wv = dinv[s];
        ushort4 v = *(const ushort4*)(hx2 + (size_t)s * NC + j * 4);
        ax = fmaf(bf2f(v.x), wv, ax); ay = fmaf(bf2f(v.y), wv, ay);
        az = fmaf(bf2f(v.z), wv, az); aw = fmaf(bf2f(v.w), wv, aw);
    }
    const float4 b = ((const float4*)b2)[j];
    float4 o;
    o.x = fmaf(ax, dn, b.x); o.y = fmaf(ay, dn, b.y);
    o.z = fmaf(az, dn, b.z); o.w = fmaf(aw, dn, b.w);
    float mx = fmaxf(fmaxf(o.x, o.y), fmaxf(o.z, o.w));
#pragma unroll
    for (int msk = 8; msk; msk >>= 1) mx = fmaxf(mx, __shfl_xor(mx, msk));
    float s4 = expf(o.x - mx) + expf(o.y - mx) + expf(o.z - mx) + expf(o.w - mx);
#pragma unroll
    for (int msk = 8; msk; msk >>= 1) s4 += __shfl_xor(s4, msk);
    float ls = mx + logf(s4);
    o.x -= ls; o.y -= ls; o.z -= ls; o.w -= ls;
    ((float4*)out)[(size_t)n * 16 + j] = o;
}

// ---------------- launch ----------------------------------------------------
extern "C" void kernel_launch(void* const* d_in, const int* in_sizes, int n_in,
                              void* d_out, int out_size, void* d_ws, size_t ws_size,
                              hipStream_t stream) {
    const float* x  = (const float*)d_in[0];
    const float* W1 = (const float*)d_in[1];
    const float* b1 = (const float*)d_in[2];
    const float* W2 = (const float*)d_in[3];
    const float* b2 = (const float*)d_in[4];
    const void*  ei = d_in[5];
    float* out = (float*)d_out;

    char* ws = (char*)d_ws;
    size_t off = 0;
    auto alloc = [&](size_t bytes) {
        char* p = ws + off;
        off += (bytes + 255) & ~(size_t)255;
        return p;
    };
    int*            mode    = (int*)            alloc(4);
    int*            deg     = (int*)            alloc((size_t)N_NODES * 4);
    int*            ptmp    = (int*)            alloc((size_t)N_NODES * 4);
    int*            bsum    = (int*)            alloc(4096);
    int*            row_ptr = (int*)            alloc((size_t)(N_NODES + 1) * 4);
    int*            cursor  = (int*)            alloc((size_t)N_NODES * 4);
    float*          dinv    = (float*)          alloc((size_t)N_NODES * 4);
    int*            csr_src = (int*)            alloc((size_t)N_EDGES * 4);
    unsigned short* W1T     = (unsigned short*) alloc((size_t)F_IN * HID * 2);
    unsigned short* W2T     = (unsigned short*) alloc((size_t)HID * NC * 2);
    unsigned short* xbf     = (unsigned short*) alloc((size_t)N_NODES * F_IN * 2);
    unsigned short* px      = (unsigned short*) alloc((size_t)(N_NODES + 64) * F_IN * 2);  // +pad rows
    unsigned short* hx2     = (unsigned short*) alloc((size_t)(N_NODES + 64) * NC * 2);
    // h buffer eliminated (fused in LDS)

    k_detect<<<1, 64, 0, stream>>>((const int*)ei, mode);

    k_zero<<<(N_NODES + 255) / 256, 256, 0, stream>>>(deg, N_NODES);
    k_hist<<<(N_EDGES + 255) / 256, 256, 0, stream>>>(ei, mode, deg);
    k_scanA<<<NB_SCAN, 256, 0, stream>>>(deg, ptmp, bsum);
    k_scanB<<<1, 512, 0, stream>>>(bsum);
    k_scanC<<<NB_SCAN, 256, 0, stream>>>(deg, ptmp, bsum, row_ptr, cursor, dinv);
    k_fill<<<(N_EDGES + 255) / 256, 256, 0, stream>>>(ei, mode, cursor, csr_src);

    // weight + input prep
    k_w1t<<<F_IN * HID / 256, 256, 0, stream>>>(W1, W1T);
    k_w2t<<<HID * NC / 256, 256, 0, stream>>>(W2, W2T);
    k_xbf<<<N_NODES * F_IN / 8 / 256, 256, 0, stream>>>(x, xbf);

    // layer 1 propagate, fused MLP (gemm1+relu+gemm2), layer 2 propagate+softmax
    k_gather1<<<N_NODES / 16, 256, 0, stream>>>(xbf, row_ptr, csr_src, dinv, px);
    k_mlp_fused<<<(N_NODES + 63) / 64, 256, 0, stream>>>(px, W1T, b1, W2T, hx2);
    k_gather2sm<<<N_NODES / 16, 256, 0, stream>>>(hx2, row_ptr, csr_src, dinv, b2, out);
}